// Round 1
// baseline (322.832 us; speedup 1.0000x reference)
//
#include <hip/hip_runtime.h>

#define POOL 7
#define NROIS 1000
#define IMG_H 128
#define IMG_W 128
#define NCH 1024

// One block (256 threads) per output cell (roi, py, px).
// Each thread: one float4 per bilinear corner + lerp + one float4 store.
__global__ __launch_bounds__(256) void roi_pool_kernel(
    const float* __restrict__ img,
    const int* __restrict__ rois,
    float* __restrict__ out)
{
    const int bid  = blockIdx.x;            // roi*49 + py*7 + px
    const int roi  = bid / 49;
    const int cell = bid - roi * 49;
    const int py   = cell / 7;
    const int px   = cell - py * 7;

    const int4 r = ((const int4*)rois)[roi];   // x, y, w, h
    const int x = r.x, y = r.y, w = r.z, h = r.w;

    // y-axis source coords (match reference op order exactly)
    const float hf = (float)h;
    float fy = ((float)py + 0.5f) * (hf / (float)POOL) - 0.5f;
    fy = fminf(fmaxf(fy, 0.0f), fmaxf(hf - 1.0f, 0.0f));
    const int   iy0 = (int)floorf(fy);
    const int   iy1 = min(iy0 + 1, h - 1);
    const float wy  = fy - (float)iy0;
    const int   y0  = y + iy0;
    const int   y1  = y + iy1;

    // x-axis source coords
    const float wf = (float)w;
    float fx = ((float)px + 0.5f) * (wf / (float)POOL) - 0.5f;
    fx = fminf(fmaxf(fx, 0.0f), fmaxf(wf - 1.0f, 0.0f));
    const int   ix0 = (int)floorf(fx);
    const int   ix1 = min(ix0 + 1, w - 1);
    const float wx  = fx - (float)ix0;
    const int   x0  = x + ix0;
    const int   x1  = x + ix1;

    const float4* p00 = (const float4*)(img + ((size_t)y0 * IMG_W + x0) * NCH);
    const float4* p01 = (const float4*)(img + ((size_t)y0 * IMG_W + x1) * NCH);
    const float4* p10 = (const float4*)(img + ((size_t)y1 * IMG_W + x0) * NCH);
    const float4* p11 = (const float4*)(img + ((size_t)y1 * IMG_W + x1) * NCH);
    float4* po = (float4*)(out + (size_t)bid * NCH);

    const int t = threadIdx.x;   // 0..255 ; 256 * float4 = 1024 channels

    const float4 a = p00[t];
    const float4 b = p01[t];
    const float4 c = p10[t];
    const float4 d = p11[t];

    const float owx = 1.0f - wx;
    const float owy = 1.0f - wy;

    float4 top, bot, res;
    top.x = a.x * owx + b.x * wx;
    top.y = a.y * owx + b.y * wx;
    top.z = a.z * owx + b.z * wx;
    top.w = a.w * owx + b.w * wx;
    bot.x = c.x * owx + d.x * wx;
    bot.y = c.y * owx + d.y * wx;
    bot.z = c.z * owx + d.z * wx;
    bot.w = c.w * owx + d.w * wx;
    res.x = top.x * owy + bot.x * wy;
    res.y = top.y * owy + bot.y * wy;
    res.z = top.z * owy + bot.z * wy;
    res.w = top.w * owy + bot.w * wy;

    po[t] = res;
}

extern "C" void kernel_launch(void* const* d_in, const int* in_sizes, int n_in,
                              void* d_out, int out_size, void* d_ws, size_t ws_size,
                              hipStream_t stream)
{
    const float* img  = (const float*)d_in[0];
    const int*   rois = (const int*)d_in[1];
    float*       out  = (float*)d_out;

    const int nblocks = NROIS * POOL * POOL;   // 49000
    roi_pool_kernel<<<nblocks, 256, 0, stream>>>(img, rois, out);
}

// Round 2
// 316.369 us; speedup vs baseline: 1.0204x; 1.0204x over previous
//
#include <hip/hip_runtime.h>

#define POOL 7
#define NROIS 1000
#define IMG_H 128
#define IMG_W 128
#define NCH 1024

typedef float f4 __attribute__((ext_vector_type(4)));

// One block (256 threads) per output cell (roi, py, px).
// Each thread: one float4 per bilinear corner + lerp + one nontemporal float4 store.
// Non-temporal stores keep the 64 MB image resident in L3 (round-1 rocprof
// showed 352 MB HBM fetch = L3 evictions driven by the 200 MB output stream).
__global__ __launch_bounds__(256) void roi_pool_kernel(
    const float* __restrict__ img,
    const int* __restrict__ rois,
    float* __restrict__ out)
{
    const int bid  = blockIdx.x;            // roi*49 + py*7 + px
    const int roi  = bid / 49;
    const int cell = bid - roi * 49;
    const int py   = cell / 7;
    const int px   = cell - py * 7;

    const int4 r = ((const int4*)rois)[roi];   // x, y, w, h
    const int x = r.x, y = r.y, w = r.z, h = r.w;

    // y-axis source coords (match reference op order exactly)
    const float hf = (float)h;
    float fy = ((float)py + 0.5f) * (hf / (float)POOL) - 0.5f;
    fy = fminf(fmaxf(fy, 0.0f), fmaxf(hf - 1.0f, 0.0f));
    const int   iy0 = (int)floorf(fy);
    const int   iy1 = min(iy0 + 1, h - 1);
    const float wy  = fy - (float)iy0;
    const int   y0  = y + iy0;
    const int   y1  = y + iy1;

    // x-axis source coords
    const float wf = (float)w;
    float fx = ((float)px + 0.5f) * (wf / (float)POOL) - 0.5f;
    fx = fminf(fmaxf(fx, 0.0f), fmaxf(wf - 1.0f, 0.0f));
    const int   ix0 = (int)floorf(fx);
    const int   ix1 = min(ix0 + 1, w - 1);
    const float wx  = fx - (float)ix0;
    const int   x0  = x + ix0;
    const int   x1  = x + ix1;

    const f4* p00 = (const f4*)(img + ((size_t)y0 * IMG_W + x0) * NCH);
    const f4* p01 = (const f4*)(img + ((size_t)y0 * IMG_W + x1) * NCH);
    const f4* p10 = (const f4*)(img + ((size_t)y1 * IMG_W + x0) * NCH);
    const f4* p11 = (const f4*)(img + ((size_t)y1 * IMG_W + x1) * NCH);
    f4* po = (f4*)(out + (size_t)bid * NCH);

    const int t = threadIdx.x;   // 0..255 ; 256 * float4 = 1024 channels

    const f4 a = p00[t];
    const f4 b = p01[t];
    const f4 c = p10[t];
    const f4 d = p11[t];

    const float owx = 1.0f - wx;
    const float owy = 1.0f - wy;

    const f4 top = a * owx + b * wx;
    const f4 bot = c * owx + d * wx;
    const f4 res = top * owy + bot * wy;

    __builtin_nontemporal_store(res, po + t);
}

extern "C" void kernel_launch(void* const* d_in, const int* in_sizes, int n_in,
                              void* d_out, int out_size, void* d_ws, size_t ws_size,
                              hipStream_t stream)
{
    const float* img  = (const float*)d_in[0];
    const int*   rois = (const int*)d_in[1];
    float*       out  = (float*)d_out;

    const int nblocks = NROIS * POOL * POOL;   // 49000
    roi_pool_kernel<<<nblocks, 256, 0, stream>>>(img, rois, out);
}

// Round 3
// 302.158 us; speedup vs baseline: 1.0684x; 1.0470x over previous
//
#include <hip/hip_runtime.h>

#define POOL 7
#define NROIS 1000
#define NCELLS (NROIS * POOL * POOL)     // 49000 output cells
#define IMG_W 128
#define NCH 1024

#define CG 32                            // channels per group (32ch*4B*16K px = 2 MB slice < 4 MB L2)
#define NG (NCH / CG)                    // 32 groups
#define CELLS_PER_BLK 32                 // 256 thr = 32 cells x 8 lanes(float4=4ch each)
#define BLKS_PER_GROUP ((NCELLS + CELLS_PER_BLK - 1) / CELLS_PER_BLK)   // 1532
#define NXCD 8
#define PHASES (NG / NXCD)               // 4 sequential channel-groups per XCD

typedef float f4 __attribute__((ext_vector_type(4)));

// Channel-sharded ROI bilinear pooling.
// bid%8 == XCD id (round-robin dispatch heuristic). XCD k processes channel
// groups {k, k+8, k+16, k+24} in sequential phases; its L2 working set is a
// single 2 MB image channel-slice shared by all 49000 cells of the group.
// Each image byte is read by exactly one XCD -> ideal L2-miss traffic = 64 MB.
__global__ __launch_bounds__(256) void roi_pool_kernel(
    const float* __restrict__ img,
    const int* __restrict__ rois,
    float* __restrict__ out)
{
    const unsigned bid   = blockIdx.x;
    const unsigned xcd   = bid & 7u;           // presumed XCD of this block
    const unsigned slot  = bid >> 3;           // per-XCD sequential slot
    const unsigned phase = slot / BLKS_PER_GROUP;
    const unsigned cblk  = slot - phase * BLKS_PER_GROUP;
    const unsigned g     = phase * NXCD + xcd; // channel group handled here

    const unsigned t    = threadIdx.x;         // 0..255
    const unsigned cell = cblk * CELLS_PER_BLK + (t >> 3);   // 8 lanes per cell
    if (cell >= NCELLS) return;

    const unsigned roi = cell / 49u;
    const unsigned c49 = cell - roi * 49u;
    const unsigned py  = c49 / 7u;
    const unsigned px  = c49 - py * 7u;

    const int4 r = ((const int4*)rois)[roi];   // x, y, w, h
    const int x = r.x, y = r.y, w = r.z, h = r.w;

    // y-axis source coords (match reference op order exactly)
    const float hf = (float)h;
    float fy = ((float)py + 0.5f) * (hf / (float)POOL) - 0.5f;
    fy = fminf(fmaxf(fy, 0.0f), fmaxf(hf - 1.0f, 0.0f));
    const int   iy0 = (int)floorf(fy);
    const int   iy1 = min(iy0 + 1, h - 1);
    const float wy  = fy - (float)iy0;
    const int   y0  = y + iy0;
    const int   y1  = y + iy1;

    // x-axis source coords
    const float wf = (float)w;
    float fx = ((float)px + 0.5f) * (wf / (float)POOL) - 0.5f;
    fx = fminf(fmaxf(fx, 0.0f), fmaxf(wf - 1.0f, 0.0f));
    const int   ix0 = (int)floorf(fx);
    const int   ix1 = min(ix0 + 1, w - 1);
    const float wx  = fx - (float)ix0;
    const int   x0  = x + ix0;
    const int   x1  = x + ix1;

    // channel offset within the image/output row: group base + lane quad
    const unsigned choff = g * CG + (t & 7u) * 4u;

    const f4* p00 = (const f4*)(img + ((size_t)y0 * IMG_W + x0) * NCH + choff);
    const f4* p01 = (const f4*)(img + ((size_t)y0 * IMG_W + x1) * NCH + choff);
    const f4* p10 = (const f4*)(img + ((size_t)y1 * IMG_W + x0) * NCH + choff);
    const f4* p11 = (const f4*)(img + ((size_t)y1 * IMG_W + x1) * NCH + choff);
    f4* po = (f4*)(out + (size_t)cell * NCH + choff);

    const f4 a = *p00;
    const f4 b = *p01;
    const f4 c = *p10;
    const f4 d = *p11;

    const float owx = 1.0f - wx;
    const float owy = 1.0f - wy;

    const f4 top = a * owx + b * wx;
    const f4 bot = c * owx + d * wx;
    const f4 res = top * owy + bot * wy;

    __builtin_nontemporal_store(res, po);
}

extern "C" void kernel_launch(void* const* d_in, const int* in_sizes, int n_in,
                              void* d_out, int out_size, void* d_ws, size_t ws_size,
                              hipStream_t stream)
{
    const float* img  = (const float*)d_in[0];
    const int*   rois = (const int*)d_in[1];
    float*       out  = (float*)d_out;

    const int nblocks = BLKS_PER_GROUP * NG;   // 1532 * 32 = 49024
    roi_pool_kernel<<<nblocks, 256, 0, stream>>>(img, rois, out);
}